// Round 1
// baseline (432.246 us; speedup 1.0000x reference)
//
#include <hip/hip_runtime.h>

// ---------------------------------------------------------------------------
// RouteGNN: 2-layer GAT (H=2, C=64, edge_dim=1, concat=False) + mean-pool + lin
// N=50000 nodes, E=800000 edges (+N self loops), G=256 graphs. All fp32.
// Strategy: build CSR by dst once per call (count/scan/fill), then each GAT
// layer = SGEMM (xp = X@W) + per-node attention dots + fused gather kernel
// (one wave per node: alpha -> softmax -> weighted row gather of xp[src]).
// ---------------------------------------------------------------------------

#define NEG_SLOPE 0.2f

__device__ __forceinline__ float wred_sum(float v) {
#pragma unroll
  for (int m = 32; m; m >>= 1) v += __shfl_xor(v, m);
  return v;
}
__device__ __forceinline__ float wred_max(float v) {
#pragma unroll
  for (int m = 32; m; m >>= 1) v = fmaxf(v, __shfl_xor(v, m));
  return v;
}
__device__ __forceinline__ float lrelu(float x) {
  return x > 0.0f ? x : NEG_SLOPE * x;
}

// ---------------- edge_attr mean (deterministic 2-stage) -------------------
__global__ void mean_partial(const float* __restrict__ ea, int E,
                             float* __restrict__ partials) {
  __shared__ float sm[256];
  float s = 0.f;
  for (int i = blockIdx.x * 256 + threadIdx.x; i < E; i += gridDim.x * 256)
    s += ea[i];
  sm[threadIdx.x] = s;
  __syncthreads();
  for (int off = 128; off; off >>= 1) {
    if (threadIdx.x < off) sm[threadIdx.x] += sm[threadIdx.x + off];
    __syncthreads();
  }
  if (threadIdx.x == 0) partials[blockIdx.x] = sm[0];
}

// params[0]=mean(edge_attr); params[1..2]=s_h layer1; params[3..4]=s_h layer2
// where s_h = sum_c We[h*64+c]*att_e[h*64+c]
__global__ void finalize_params(const float* __restrict__ partials, int nparts,
                                int E, const float* __restrict__ We1,
                                const float* __restrict__ atte1,
                                const float* __restrict__ We2,
                                const float* __restrict__ atte2,
                                float* __restrict__ params) {
  __shared__ float sm[256];
  int t = threadIdx.x;
  float s = 0.f;
  for (int i = t; i < nparts; i += 256) s += partials[i];
  sm[t] = s;
  __syncthreads();
  for (int off = 128; off; off >>= 1) {
    if (t < off) sm[t] += sm[t + off];
    __syncthreads();
  }
  if (t == 0) params[0] = sm[0] / (float)E;
  __syncthreads();
  int l = t >> 7, h = (t >> 6) & 1, c = t & 63;
  float p = (l == 0) ? We1[h * 64 + c] * atte1[h * 64 + c]
                     : We2[h * 64 + c] * atte2[h * 64 + c];
  sm[t] = p;
  __syncthreads();
  for (int off = 32; off; off >>= 1) {
    if (c < off) sm[t] += sm[t + off];
    __syncthreads();
  }
  if (c == 0) params[1 + l * 2 + h] = sm[t];
}

// ---------------- CSR build (by dst) ---------------------------------------
__global__ void count_edges(const int* __restrict__ ei, int E,
                            int* __restrict__ counts) {
  int i = blockIdx.x * blockDim.x + threadIdx.x;
  if (i < E) atomicAdd(&counts[ei[E + i]], 1);
}

// single block, 1024 threads; rowstart[n+1]-rowstart[n] = counts[n]+1 (selfloop)
__global__ void scan_rowstart(const int* __restrict__ counts,
                              int* __restrict__ rowstart, int N) {
  __shared__ int sd[1024];
  int t = threadIdx.x;
  const int CH = (N + 1023) / 1024;
  int b = t * CH, e = min(b + CH, N);
  int s = 0;
  for (int i = b; i < e; ++i) s += counts[i] + 1;
  sd[t] = s;
  __syncthreads();
  for (int off = 1; off < 1024; off <<= 1) {
    int v = (t >= off) ? sd[t - off] : 0;
    __syncthreads();
    sd[t] += v;
    __syncthreads();
  }
  int run = (t == 0) ? 0 : sd[t - 1];
  if (t == 0) rowstart[0] = 0;
  for (int i = b; i < e; ++i) {
    run += counts[i] + 1;
    rowstart[i + 1] = run;
  }
}

__global__ void fill_edges(const int* __restrict__ ei,
                           const float* __restrict__ eattr, int E,
                           const int* __restrict__ rowstart,
                           int* __restrict__ fills, int* __restrict__ srcs,
                           float* __restrict__ eas) {
  int i = blockIdx.x * blockDim.x + threadIdx.x;
  if (i < E) {
    int d = ei[E + i];
    int pos = rowstart[d] + atomicAdd(&fills[d], 1);
    srcs[pos] = ei[i];
    eas[pos] = eattr[i];
  }
}

__global__ void fill_selfloops(int N, const int* __restrict__ rowstart,
                               const float* __restrict__ params,
                               int* __restrict__ srcs,
                               float* __restrict__ eas) {
  int n = blockIdx.x * blockDim.x + threadIdx.x;
  if (n < N) {
    int pos = rowstart[n + 1] - 1;
    srcs[pos] = n;
    eas[pos] = params[0];
  }
}

// ---------------- SGEMM: Y[N,128] = X[N,K] @ W[K,128], K in {64,128} --------
#define BM 64
#define BK 32
__global__ __launch_bounds__(256) void gemm_x_w(const float* __restrict__ X,
                                                const float* __restrict__ W,
                                                float* __restrict__ Y, int N,
                                                int K) {
  __shared__ float As[BK][BM + 1];  // transposed A tile
  __shared__ float Bs[BK][128];
  int t = threadIdx.x;
  int tx = t & 15;  // col group: cols tx*8 .. tx*8+7
  int ty = t >> 4;  // row group: rows ty*4 .. ty*4+3
  int rowBase = blockIdx.x * BM;
  float acc[4][8];
#pragma unroll
  for (int r = 0; r < 4; ++r)
#pragma unroll
    for (int c = 0; c < 8; ++c) acc[r][c] = 0.f;

  for (int k0 = 0; k0 < K; k0 += BK) {
    // A tile: BM x BK = 512 float4
#pragma unroll
    for (int v = t; v < BM * BK / 4; v += 256) {
      int r = v >> 3;       // 8 float4 per row
      int cv = v & 7;
      int gr = rowBase + r;
      float4 a = make_float4(0.f, 0.f, 0.f, 0.f);
      if (gr < N) a = *(const float4*)(X + (size_t)gr * K + k0 + cv * 4);
      As[cv * 4 + 0][r] = a.x;
      As[cv * 4 + 1][r] = a.y;
      As[cv * 4 + 2][r] = a.z;
      As[cv * 4 + 3][r] = a.w;
    }
    // B tile: BK x 128 = 1024 float4
#pragma unroll
    for (int v = t; v < BK * 128 / 4; v += 256) {
      int r = v >> 5;  // 32 float4 per row
      int cv = v & 31;
      *(float4*)&Bs[r][cv * 4] =
          *(const float4*)(W + (size_t)(k0 + r) * 128 + cv * 4);
    }
    __syncthreads();
#pragma unroll
    for (int kk = 0; kk < BK; ++kk) {
      float a[4], b[8];
#pragma unroll
      for (int r = 0; r < 4; ++r) a[r] = As[kk][ty * 4 + r];
#pragma unroll
      for (int c = 0; c < 8; ++c) b[c] = Bs[kk][tx * 8 + c];
#pragma unroll
      for (int r = 0; r < 4; ++r)
#pragma unroll
        for (int c = 0; c < 8; ++c) acc[r][c] = fmaf(a[r], b[c], acc[r][c]);
    }
    __syncthreads();
  }
#pragma unroll
  for (int r = 0; r < 4; ++r) {
    int gr = rowBase + ty * 4 + r;
    if (gr < N) {
      float4 o0 = make_float4(acc[r][0], acc[r][1], acc[r][2], acc[r][3]);
      float4 o1 = make_float4(acc[r][4], acc[r][5], acc[r][6], acc[r][7]);
      *(float4*)(Y + (size_t)gr * 128 + tx * 8) = o0;
      *(float4*)(Y + (size_t)gr * 128 + tx * 8 + 4) = o1;
    }
  }
}

// ---------------- per-node attention dots -----------------------------------
// a_src[n][h] = sum_c xp[n][h*64+c]*att_src[h*64+c]; same for dst. Wave/node.
__global__ void attn_node(const float* __restrict__ xp,
                          const float* __restrict__ att_src,
                          const float* __restrict__ att_dst,
                          float* __restrict__ a_src, float* __restrict__ a_dst,
                          int N) {
  int wid = threadIdx.x >> 6, lane = threadIdx.x & 63;
  int n = blockIdx.x * 4 + wid;
  if (n >= N) return;
  float v0 = xp[(size_t)n * 128 + lane];
  float v1 = xp[(size_t)n * 128 + 64 + lane];
  float ps0 = wred_sum(v0 * att_src[lane]);
  float ps1 = wred_sum(v1 * att_src[64 + lane]);
  float pd0 = wred_sum(v0 * att_dst[lane]);
  float pd1 = wred_sum(v1 * att_dst[64 + lane]);
  if (lane == 0) {
    a_src[n * 2 + 0] = ps0;
    a_src[n * 2 + 1] = ps1;
    a_dst[n * 2 + 0] = pd0;
    a_dst[n * 2 + 1] = pd1;
  }
}

// ---------------- fused gather: softmax-attention aggregate ----------------
// One wave per node. lane = output channel c (0..63), both heads handled.
// If hout != null: write relu(out)+... to hout[N,64]  (layer 1)
// else: epilogue dot with lin_w -> dotout[n]           (layer 2)
__global__ void gat_gather(const int* __restrict__ rowstart,
                           const int* __restrict__ srcs,
                           const float* __restrict__ eas,
                           const float* __restrict__ xp,
                           const float* __restrict__ a_src,
                           const float* __restrict__ a_dst,
                           const float* __restrict__ params, int sbase,
                           const float* __restrict__ bias,
                           float* __restrict__ hout,
                           const float* __restrict__ lin_w,
                           float* __restrict__ dotout, int N) {
  int wid = threadIdx.x >> 6, lane = threadIdx.x & 63;
  int n = blockIdx.x * 4 + wid;
  if (n >= N) return;
  int beg = rowstart[n], end = rowstart[n + 1];
  int deg = end - beg;
  float s0 = params[sbase], s1 = params[sbase + 1];
  float ad0 = a_dst[n * 2 + 0], ad1 = a_dst[n * 2 + 1];

  bool fast = (deg <= 64);
  float al0 = -1e30f, al1 = -1e30f;
  int myS = n;
  float m0 = -1e30f, m1 = -1e30f;

  if (fast) {
    if (lane < deg) {
      int e = beg + lane;
      myS = srcs[e];
      float eav = eas[e];
      al0 = lrelu(a_src[myS * 2 + 0] + ad0 + eav * s0);
      al1 = lrelu(a_src[myS * 2 + 1] + ad1 + eav * s1);
      m0 = al0;
      m1 = al1;
    }
  } else {
    for (int e = beg + lane; e < end; e += 64) {
      int s = srcs[e];
      float eav = eas[e];
      m0 = fmaxf(m0, lrelu(a_src[s * 2 + 0] + ad0 + eav * s0));
      m1 = fmaxf(m1, lrelu(a_src[s * 2 + 1] + ad1 + eav * s1));
    }
  }
  m0 = wred_max(m0);
  m1 = wred_max(m1);

  float sum0 = 0.f, sum1 = 0.f;
  if (fast) {
    sum0 = __expf(al0 - m0) == 0.f ? expf(al0 - m0) : expf(al0 - m0);
    sum0 = expf(al0 - m0);
    sum1 = expf(al1 - m1);
  } else {
    for (int e = beg + lane; e < end; e += 64) {
      int s = srcs[e];
      float eav = eas[e];
      float t0 = lrelu(a_src[s * 2 + 0] + ad0 + eav * s0);
      float t1 = lrelu(a_src[s * 2 + 1] + ad1 + eav * s1);
      sum0 += expf(t0 - m0);
      sum1 += expf(t1 - m1);
    }
  }
  sum0 = wred_sum(sum0);
  sum1 = wred_sum(sum1);
  float inv0 = 1.f / sum0, inv1 = 1.f / sum1;

  float acc0 = 0.f, acc1 = 0.f;
  for (int base = beg; base < end; base += 64) {
    float c0 = 0.f, c1 = 0.f;
    int cs = n;
    if (fast) {
      c0 = expf(al0 - m0) * inv0;  // lanes >= deg: exp(-huge) = 0
      c1 = expf(al1 - m1) * inv1;
      cs = myS;
    } else {
      int e = base + lane;
      if (e < end) {
        int s = srcs[e];
        float eav = eas[e];
        float t0 = lrelu(a_src[s * 2 + 0] + ad0 + eav * s0);
        float t1 = lrelu(a_src[s * 2 + 1] + ad1 + eav * s1);
        c0 = expf(t0 - m0) * inv0;
        c1 = expf(t1 - m1) * inv1;
        cs = s;
      }
    }
    int cnt = min(64, end - base);
    for (int i = 0; i < cnt; ++i) {
      float cc0 = __shfl(c0, i);
      float cc1 = __shfl(c1, i);
      int s2 = __shfl(cs, i);
      const float* row = xp + (size_t)s2 * 128;
      acc0 = fmaf(cc0, row[lane], acc0);
      acc1 = fmaf(cc1, row[64 + lane], acc1);
    }
  }

  float val = 0.5f * (acc0 + acc1) + bias[lane];
  val = fmaxf(val, 0.f);  // relu after both layers
  if (hout) {
    hout[(size_t)n * 64 + lane] = val;
  } else {
    float p = wred_sum(val * lin_w[lane]);
    if (lane == 0) dotout[n] = p;
  }
}

// ---------------- pooling + final linear ------------------------------------
__device__ __forceinline__ int lowerb(const int* b, int n, int v) {
  int lo = 0, hi = n;
  while (lo < hi) {
    int mid = (lo + hi) >> 1;
    if (b[mid] < v)
      lo = mid + 1;
    else
      hi = mid;
  }
  return lo;
}

__global__ void pool_lin(const float* __restrict__ dot,
                         const int* __restrict__ batch, int N, int G,
                         const float* __restrict__ lin_b,
                         float* __restrict__ out) {
  int g = blockIdx.x;
  int lane = threadIdx.x;
  int beg = lowerb(batch, N, g);
  int end = lowerb(batch, N, g + 1);
  float s = 0.f;
  for (int i = beg + lane; i < end; i += 64) s += dot[i];
  s = wred_sum(s);
  if (lane == 0) {
    float cnt = fmaxf((float)(end - beg), 1.0f);
    out[g] = s / cnt + lin_b[0];
  }
}

// ---------------------------------------------------------------------------
extern "C" void kernel_launch(void* const* d_in, const int* in_sizes, int n_in,
                              void* d_out, int out_size, void* d_ws,
                              size_t ws_size, hipStream_t stream) {
  const float* x = (const float*)d_in[0];
  const int* ei = (const int*)d_in[1];
  const float* eattr = (const float*)d_in[2];
  const int* batch = (const int*)d_in[3];
  const float* W1 = (const float*)d_in[4];
  const float* att_src1 = (const float*)d_in[5];
  const float* att_dst1 = (const float*)d_in[6];
  const float* We1 = (const float*)d_in[7];
  const float* att_e1 = (const float*)d_in[8];
  const float* b1 = (const float*)d_in[9];
  const float* W2 = (const float*)d_in[10];
  const float* att_src2 = (const float*)d_in[11];
  const float* att_dst2 = (const float*)d_in[12];
  const float* We2 = (const float*)d_in[13];
  const float* att_e2 = (const float*)d_in[14];
  const float* b2 = (const float*)d_in[15];
  const float* lin_w = (const float*)d_in[16];
  const float* lin_b = (const float*)d_in[17];
  float* out = (float*)d_out;

  const int Nn = in_sizes[0] / 128;   // 50000
  const int Ee = in_sizes[2];         // 800000
  const int Etot = Ee + Nn;
  const int Gg = out_size;            // 256

  char* ws = (char*)d_ws;
  size_t off = 0;
  auto alloc = [&](size_t bytes) -> char* {
    char* p = ws + off;
    off += (bytes + 255) & ~(size_t)255;
    return p;
  };
  float* params = (float*)alloc(8 * 4);
  float* partials = (float*)alloc(512 * 4);
  int* counts = (int*)alloc((size_t)Nn * 4);
  int* fills = (int*)alloc((size_t)Nn * 4);
  int* rowstart = (int*)alloc((size_t)(Nn + 1) * 4);
  int* srcs = (int*)alloc((size_t)Etot * 4);
  float* eas = (float*)alloc((size_t)Etot * 4);
  float* a_src = (float*)alloc((size_t)Nn * 2 * 4);
  float* a_dst = (float*)alloc((size_t)Nn * 2 * 4);
  float* xp = (float*)alloc((size_t)Nn * 128 * 4);
  float* h1 = (float*)alloc((size_t)Nn * 64 * 4);
  float* dotv = (float*)alloc((size_t)Nn * 4);

  hipMemsetAsync(counts, 0, (size_t)Nn * 4, stream);
  hipMemsetAsync(fills, 0, (size_t)Nn * 4, stream);

  // params
  mean_partial<<<512, 256, 0, stream>>>(eattr, Ee, partials);
  finalize_params<<<1, 256, 0, stream>>>(partials, 512, Ee, We1, att_e1, We2,
                                         att_e2, params);
  // CSR by dst
  count_edges<<<(Ee + 255) / 256, 256, 0, stream>>>(ei, Ee, counts);
  scan_rowstart<<<1, 1024, 0, stream>>>(counts, rowstart, Nn);
  fill_edges<<<(Ee + 255) / 256, 256, 0, stream>>>(ei, eattr, Ee, rowstart,
                                                   fills, srcs, eas);
  fill_selfloops<<<(Nn + 255) / 256, 256, 0, stream>>>(Nn, rowstart, params,
                                                       srcs, eas);

  // ---- layer 1 ----
  gemm_x_w<<<(Nn + BM - 1) / BM, 256, 0, stream>>>(x, W1, xp, Nn, 128);
  attn_node<<<(Nn + 3) / 4, 256, 0, stream>>>(xp, att_src1, att_dst1, a_src,
                                              a_dst, Nn);
  gat_gather<<<(Nn + 3) / 4, 256, 0, stream>>>(rowstart, srcs, eas, xp, a_src,
                                               a_dst, params, 1, b1, h1,
                                               nullptr, nullptr, Nn);
  // ---- layer 2 ----
  gemm_x_w<<<(Nn + BM - 1) / BM, 256, 0, stream>>>(h1, W2, xp, Nn, 64);
  attn_node<<<(Nn + 3) / 4, 256, 0, stream>>>(xp, att_src2, att_dst2, a_src,
                                              a_dst, Nn);
  gat_gather<<<(Nn + 3) / 4, 256, 0, stream>>>(rowstart, srcs, eas, xp, a_src,
                                               a_dst, params, 3, b2, nullptr,
                                               lin_w, dotv, Nn);
  // ---- pool + linear ----
  pool_lin<<<Gg, 64, 0, stream>>>(dotv, batch, Nn, Gg, lin_b, out);
}

// Round 2
// 315.044 us; speedup vs baseline: 1.3720x; 1.3720x over previous
//
#include <hip/hip_runtime.h>

// ---------------------------------------------------------------------------
// RouteGNN: 2-layer GAT (H=2, C=64, edge_dim=1, concat=False) + mean-pool + lin
// N=50000 nodes, E=800000 edges (+N self loops), G=256 graphs. All fp32.
// R1: atomic CSR allocation (no serial scan), attn dots fused into GEMM
// epilogue, gather loop = 2 edges/iter float4 with LDS-staged coefficients.
// ---------------------------------------------------------------------------

#define NEG_SLOPE 0.2f

__device__ __forceinline__ float wred_sum(float v) {
#pragma unroll
  for (int m = 32; m; m >>= 1) v += __shfl_xor(v, m);
  return v;
}
__device__ __forceinline__ float wred_max(float v) {
#pragma unroll
  for (int m = 32; m; m >>= 1) v = fmaxf(v, __shfl_xor(v, m));
  return v;
}
__device__ __forceinline__ float lrelu(float x) {
  return x > 0.0f ? x : NEG_SLOPE * x;
}

// ---------------- edge mean partials + dst-degree counts -------------------
__global__ void mean_count(const int* __restrict__ ei,
                           const float* __restrict__ ea, int E,
                           float* __restrict__ partials,
                           int* __restrict__ counts) {
  __shared__ float sm[256];
  int i = blockIdx.x * 256 + threadIdx.x;
  float v = 0.f;
  if (i < E) {
    v = ea[i];
    atomicAdd(&counts[ei[E + i]], 1);
  }
  sm[threadIdx.x] = v;
  __syncthreads();
  for (int off = 128; off; off >>= 1) {
    if (threadIdx.x < off) sm[threadIdx.x] += sm[threadIdx.x + off];
    __syncthreads();
  }
  if (threadIdx.x == 0) partials[blockIdx.x] = sm[0];
}

// params[0]=mean(edge_attr); params[1..2]=s_h layer1; params[3..4]=s_h layer2
__global__ void finalize_params(const float* __restrict__ partials, int nparts,
                                int E, const float* __restrict__ We1,
                                const float* __restrict__ atte1,
                                const float* __restrict__ We2,
                                const float* __restrict__ atte2,
                                float* __restrict__ params) {
  __shared__ float sm[256];
  int t = threadIdx.x;
  float s = 0.f;
  for (int i = t; i < nparts; i += 256) s += partials[i];
  sm[t] = s;
  __syncthreads();
  for (int off = 128; off; off >>= 1) {
    if (t < off) sm[t] += sm[t + off];
    __syncthreads();
  }
  if (t == 0) params[0] = sm[0] / (float)E;
  __syncthreads();
  int l = t >> 7, h = (t >> 6) & 1, c = t & 63;
  float p = (l == 0) ? We1[h * 64 + c] * atte1[h * 64 + c]
                     : We2[h * 64 + c] * atte2[h * 64 + c];
  sm[t] = p;
  __syncthreads();
  for (int off = 32; off; off >>= 1) {
    if (c < off) sm[t] += sm[t + off];
    __syncthreads();
  }
  if (c == 0) params[1 + l * 2 + h] = sm[t];
}

// ---------------- CSR segment allocation (atomic cursor) -------------------
// rowstart[n] = atomic alloc of counts[n]+1 slots; self-loop goes at the end
// of the segment (deterministic position within the segment).
__global__ void alloc_rows(int N, const int* __restrict__ counts,
                           int* __restrict__ cursor, int* __restrict__ rowstart,
                           const float* __restrict__ params,
                           int* __restrict__ srcs, float* __restrict__ eas) {
  int n = blockIdx.x * 256 + threadIdx.x;
  if (n < N) {
    int c = counts[n];
    int pos = atomicAdd(cursor, c + 1);
    rowstart[n] = pos;
    srcs[pos + c] = n;
    eas[pos + c] = params[0];
  }
}

__global__ void fill_edges(const int* __restrict__ ei,
                           const float* __restrict__ eattr, int E,
                           const int* __restrict__ rowstart,
                           int* __restrict__ fills, int* __restrict__ srcs,
                           float* __restrict__ eas) {
  int i = blockIdx.x * blockDim.x + threadIdx.x;
  if (i < E) {
    int d = ei[E + i];
    int pos = rowstart[d] + atomicAdd(&fills[d], 1);
    srcs[pos] = ei[i];
    eas[pos] = eattr[i];
  }
}

// ---------------- SGEMM + fused attention dots -----------------------------
// Y[N,128] = X[N,K] @ W[K,128], K in {64,128}; epilogue computes
// a_src[n][h] = sum_c Y[n][h*64+c]*att_src[h*64+c] (same for dst).
#define BM 64
#define BK 32
__global__ __launch_bounds__(256) void gemm_attn(
    const float* __restrict__ X, const float* __restrict__ W,
    const float* __restrict__ att_src, const float* __restrict__ att_dst,
    float* __restrict__ Y, float* __restrict__ a_src,
    float* __restrict__ a_dst, int N, int K) {
  __shared__ float As[BK][BM + 1];
  __shared__ float Bs[BK][128];
  int t = threadIdx.x;
  int tx = t & 15;  // cols tx*8 .. tx*8+7
  int ty = t >> 4;  // rows ty*4 .. ty*4+3
  int rowBase = blockIdx.x * BM;
  float acc[4][8];
#pragma unroll
  for (int r = 0; r < 4; ++r)
#pragma unroll
    for (int c = 0; c < 8; ++c) acc[r][c] = 0.f;

  for (int k0 = 0; k0 < K; k0 += BK) {
#pragma unroll
    for (int v = t; v < BM * BK / 4; v += 256) {
      int r = v >> 3;
      int cv = v & 7;
      int gr = rowBase + r;
      float4 a = make_float4(0.f, 0.f, 0.f, 0.f);
      if (gr < N) a = *(const float4*)(X + (size_t)gr * K + k0 + cv * 4);
      As[cv * 4 + 0][r] = a.x;
      As[cv * 4 + 1][r] = a.y;
      As[cv * 4 + 2][r] = a.z;
      As[cv * 4 + 3][r] = a.w;
    }
#pragma unroll
    for (int v = t; v < BK * 128 / 4; v += 256) {
      int r = v >> 5;
      int cv = v & 31;
      *(float4*)&Bs[r][cv * 4] =
          *(const float4*)(W + (size_t)(k0 + r) * 128 + cv * 4);
    }
    __syncthreads();
#pragma unroll
    for (int kk = 0; kk < BK; ++kk) {
      float a[4], b[8];
#pragma unroll
      for (int r = 0; r < 4; ++r) a[r] = As[kk][ty * 4 + r];
#pragma unroll
      for (int c = 0; c < 8; ++c) b[c] = Bs[kk][tx * 8 + c];
#pragma unroll
      for (int r = 0; r < 4; ++r)
#pragma unroll
        for (int c = 0; c < 8; ++c) acc[r][c] = fmaf(a[r], b[c], acc[r][c]);
    }
    __syncthreads();
  }

  // attention-dot epilogue: per-thread partials over its 8 cols (one head)
  float attS[8], attD[8];
#pragma unroll
  for (int c = 0; c < 8; ++c) {
    attS[c] = att_src[tx * 8 + c];
    attD[c] = att_dst[tx * 8 + c];
  }
#pragma unroll
  for (int r = 0; r < 4; ++r) {
    int gr = rowBase + ty * 4 + r;
    float ps = 0.f, pd = 0.f;
#pragma unroll
    for (int c = 0; c < 8; ++c) {
      ps = fmaf(acc[r][c], attS[c], ps);
      pd = fmaf(acc[r][c], attD[c], pd);
    }
    // reduce across the 8 lanes sharing (row, head): lanes differ in tx&7
#pragma unroll
    for (int m = 1; m < 8; m <<= 1) {
      ps += __shfl_xor(ps, m);
      pd += __shfl_xor(pd, m);
    }
    if (gr < N) {
      if ((t & 7) == 0) {
        int h = (t >> 3) & 1;
        a_src[gr * 2 + h] = ps;
        a_dst[gr * 2 + h] = pd;
      }
      float4 o0 = make_float4(acc[r][0], acc[r][1], acc[r][2], acc[r][3]);
      float4 o1 = make_float4(acc[r][4], acc[r][5], acc[r][6], acc[r][7]);
      *(float4*)(Y + (size_t)gr * 128 + tx * 8) = o0;
      *(float4*)(Y + (size_t)gr * 128 + tx * 8 + 4) = o1;
    }
  }
}

// ---------------- fused gather: softmax-attention aggregate ----------------
// One wave per node. Fast path (deg<=64): coefficients staged in LDS,
// 2 edges/iteration with float4 row gathers (1 KB per load instruction).
__global__ void gat_gather(const int* __restrict__ rowstart,
                           const int* __restrict__ counts,
                           const int* __restrict__ srcs,
                           const float* __restrict__ eas,
                           const float* __restrict__ xp,
                           const float* __restrict__ a_src,
                           const float* __restrict__ a_dst,
                           const float* __restrict__ params, int sbase,
                           const float* __restrict__ bias,
                           float* __restrict__ hout,
                           const float* __restrict__ lin_w,
                           float* __restrict__ dotout, int N) {
  __shared__ float sm_c[4][128];
  __shared__ int sm_s[4][64];
  int wid = threadIdx.x >> 6, lane = threadIdx.x & 63;
  int n = blockIdx.x * 4 + wid;
  if (n >= N) return;
  int beg = rowstart[n];
  int deg = counts[n] + 1;  // includes self-loop
  float s0 = params[sbase], s1 = params[sbase + 1];
  float ad0 = a_dst[n * 2 + 0], ad1 = a_dst[n * 2 + 1];

  if (deg <= 64) {
    float al0 = -1e30f, al1 = -1e30f;
    int myS = n;
    if (lane < deg) {
      int e = beg + lane;
      myS = srcs[e];
      float eav = eas[e];
      float2 as = *(const float2*)(a_src + (size_t)myS * 2);
      al0 = lrelu(as.x + ad0 + eav * s0);
      al1 = lrelu(as.y + ad1 + eav * s1);
    }
    float m0 = wred_max(al0), m1 = wred_max(al1);
    float e0 = __expf(al0 - m0), e1 = __expf(al1 - m1);  // 0 for idle lanes
    float sum0 = wred_sum(e0), sum1 = wred_sum(e1);
    float c0 = e0 / sum0, c1 = e1 / sum1;
    sm_c[wid][lane * 2 + 0] = c0;
    sm_c[wid][lane * 2 + 1] = c1;
    sm_s[wid][lane] = myS;
    // same-wave LDS producer/consumer: no barrier needed

    int half = lane >> 5;      // which edge of the pair
    int l5 = lane & 31;        // float4 index within the 128-float row
    int h = (lane >> 4) & 1;   // head of my channels
    float4 acc = make_float4(0.f, 0.f, 0.f, 0.f);
    int iters = (deg + 1) >> 1;

    int e = half;
    int s = sm_s[wid][e];
    float c = sm_c[wid][e * 2 + h];
    float4 v = ((const float4*)(xp + (size_t)s * 128))[l5];
    for (int i = 1; i < iters; ++i) {
      int e2 = 2 * i + half;
      int s2 = sm_s[wid][e2];
      float c2 = sm_c[wid][e2 * 2 + h];
      float4 v2 = ((const float4*)(xp + (size_t)s2 * 128))[l5];
      acc.x = fmaf(c, v.x, acc.x);
      acc.y = fmaf(c, v.y, acc.y);
      acc.z = fmaf(c, v.z, acc.z);
      acc.w = fmaf(c, v.w, acc.w);
      c = c2;
      v = v2;
    }
    acc.x = fmaf(c, v.x, acc.x);
    acc.y = fmaf(c, v.y, acc.y);
    acc.z = fmaf(c, v.z, acc.z);
    acc.w = fmaf(c, v.w, acc.w);

    // combine the two edge-halves (lanes l and l^32)
    acc.x += __shfl_xor(acc.x, 32);
    acc.y += __shfl_xor(acc.y, 32);
    acc.z += __shfl_xor(acc.z, 32);
    acc.w += __shfl_xor(acc.w, 32);
    // head mean: channel c (head0, lanes l5<16) with 64+c (head1, l5+16)
    float4 oth;
    oth.x = __shfl_xor(acc.x, 16);
    oth.y = __shfl_xor(acc.y, 16);
    oth.z = __shfl_xor(acc.z, 16);
    oth.w = __shfl_xor(acc.w, 16);

    float p = 0.f;
    if (lane < 16) {
      float4 b = *(const float4*)(bias + lane * 4);
      float4 o;
      o.x = fmaxf(0.5f * (acc.x + oth.x) + b.x, 0.f);
      o.y = fmaxf(0.5f * (acc.y + oth.y) + b.y, 0.f);
      o.z = fmaxf(0.5f * (acc.z + oth.z) + b.z, 0.f);
      o.w = fmaxf(0.5f * (acc.w + oth.w) + b.w, 0.f);
      if (hout) {
        *(float4*)(hout + (size_t)n * 64 + lane * 4) = o;
      } else {
        float4 lw = *(const float4*)(lin_w + lane * 4);
        p = o.x * lw.x + o.y * lw.y + o.z * lw.z + o.w * lw.w;
      }
    }
    if (!hout) {
      p = wred_sum(p);
      if (lane == 0) dotout[n] = p;
    }
  } else {
    // slow path (deg > 64): streaming two-pass, lane = channel
    int end = beg + deg;
    float m0 = -1e30f, m1 = -1e30f;
    for (int e = beg + lane; e < end; e += 64) {
      int s = srcs[e];
      float eav = eas[e];
      float2 as = *(const float2*)(a_src + (size_t)s * 2);
      m0 = fmaxf(m0, lrelu(as.x + ad0 + eav * s0));
      m1 = fmaxf(m1, lrelu(as.y + ad1 + eav * s1));
    }
    m0 = wred_max(m0);
    m1 = wred_max(m1);
    float sum0 = 0.f, sum1 = 0.f;
    for (int e = beg + lane; e < end; e += 64) {
      int s = srcs[e];
      float eav = eas[e];
      float2 as = *(const float2*)(a_src + (size_t)s * 2);
      sum0 += __expf(lrelu(as.x + ad0 + eav * s0) - m0);
      sum1 += __expf(lrelu(as.y + ad1 + eav * s1) - m1);
    }
    sum0 = wred_sum(sum0);
    sum1 = wred_sum(sum1);
    float inv0 = 1.f / sum0, inv1 = 1.f / sum1;
    float acc0 = 0.f, acc1 = 0.f;
    for (int base = beg; base < end; base += 64) {
      float c0 = 0.f, c1 = 0.f;
      int cs = n;
      int e = base + lane;
      if (e < end) {
        int s = srcs[e];
        float eav = eas[e];
        float2 as = *(const float2*)(a_src + (size_t)s * 2);
        c0 = __expf(lrelu(as.x + ad0 + eav * s0) - m0) * inv0;
        c1 = __expf(lrelu(as.y + ad1 + eav * s1) - m1) * inv1;
        cs = s;
      }
      int cnt = min(64, end - base);
      for (int i = 0; i < cnt; ++i) {
        float cc0 = __shfl(c0, i);
        float cc1 = __shfl(c1, i);
        int s2 = __shfl(cs, i);
        const float* row = xp + (size_t)s2 * 128;
        acc0 = fmaf(cc0, row[lane], acc0);
        acc1 = fmaf(cc1, row[64 + lane], acc1);
      }
    }
    float val = fmaxf(0.5f * (acc0 + acc1) + bias[lane], 0.f);
    if (hout) {
      hout[(size_t)n * 64 + lane] = val;
    } else {
      float p = wred_sum(val * lin_w[lane]);
      if (lane == 0) dotout[n] = p;
    }
  }
}

// ---------------- pooling + final linear ------------------------------------
__device__ __forceinline__ int lowerb(const int* b, int n, int v) {
  int lo = 0, hi = n;
  while (lo < hi) {
    int mid = (lo + hi) >> 1;
    if (b[mid] < v)
      lo = mid + 1;
    else
      hi = mid;
  }
  return lo;
}

__global__ void pool_lin(const float* __restrict__ dot,
                         const int* __restrict__ batch, int N, int G,
                         const float* __restrict__ lin_b,
                         float* __restrict__ out) {
  int g = blockIdx.x;
  int lane = threadIdx.x;
  int beg = lowerb(batch, N, g);
  int end = lowerb(batch, N, g + 1);
  float s = 0.f;
  for (int i = beg + lane; i < end; i += 64) s += dot[i];
  s = wred_sum(s);
  if (lane == 0) {
    float cnt = fmaxf((float)(end - beg), 1.0f);
    out[g] = s / cnt + lin_b[0];
  }
}

// ---------------------------------------------------------------------------
extern "C" void kernel_launch(void* const* d_in, const int* in_sizes, int n_in,
                              void* d_out, int out_size, void* d_ws,
                              size_t ws_size, hipStream_t stream) {
  const float* x = (const float*)d_in[0];
  const int* ei = (const int*)d_in[1];
  const float* eattr = (const float*)d_in[2];
  const int* batch = (const int*)d_in[3];
  const float* W1 = (const float*)d_in[4];
  const float* att_src1 = (const float*)d_in[5];
  const float* att_dst1 = (const float*)d_in[6];
  const float* We1 = (const float*)d_in[7];
  const float* att_e1 = (const float*)d_in[8];
  const float* b1 = (const float*)d_in[9];
  const float* W2 = (const float*)d_in[10];
  const float* att_src2 = (const float*)d_in[11];
  const float* att_dst2 = (const float*)d_in[12];
  const float* We2 = (const float*)d_in[13];
  const float* att_e2 = (const float*)d_in[14];
  const float* b2 = (const float*)d_in[15];
  const float* lin_w = (const float*)d_in[16];
  const float* lin_b = (const float*)d_in[17];
  float* out = (float*)d_out;

  const int Nn = in_sizes[0] / 128;  // 50000
  const int Ee = in_sizes[2];        // 800000
  const int Etot = Ee + Nn;
  const int Gg = out_size;           // 256
  const int mcBlocks = (Ee + 255) / 256;

  char* ws = (char*)d_ws;
  size_t off = 0;
  auto alloc = [&](size_t bytes) -> char* {
    char* p = ws + off;
    off += (bytes + 255) & ~(size_t)255;
    return p;
  };
  float* params = (float*)alloc(8 * 4);
  float* partials = (float*)alloc((size_t)(mcBlocks + 64) * 4);
  int* counts = (int*)alloc((size_t)(2 * Nn + 64) * 4);  // counts|fills|cursor
  int* fills = counts + Nn;
  int* cursor = counts + 2 * Nn;
  int* rowstart = (int*)alloc((size_t)Nn * 4);
  int* srcs = (int*)alloc((size_t)Etot * 4);
  float* eas = (float*)alloc((size_t)Etot * 4);
  float* a_src = (float*)alloc((size_t)Nn * 2 * 4);
  float* a_dst = (float*)alloc((size_t)Nn * 2 * 4);
  float* xp = (float*)alloc((size_t)Nn * 128 * 4);
  float* h1 = (float*)alloc((size_t)Nn * 64 * 4);
  float* dotv = (float*)alloc((size_t)Nn * 4);

  hipMemsetAsync(counts, 0, (size_t)(2 * Nn + 64) * 4, stream);

  mean_count<<<mcBlocks, 256, 0, stream>>>(ei, eattr, Ee, partials, counts);
  finalize_params<<<1, 256, 0, stream>>>(partials, mcBlocks, Ee, We1, att_e1,
                                         We2, att_e2, params);
  alloc_rows<<<(Nn + 255) / 256, 256, 0, stream>>>(Nn, counts, cursor,
                                                   rowstart, params, srcs, eas);
  fill_edges<<<mcBlocks, 256, 0, stream>>>(ei, eattr, Ee, rowstart, fills,
                                           srcs, eas);

  // ---- layer 1 ----
  gemm_attn<<<(Nn + BM - 1) / BM, 256, 0, stream>>>(
      x, W1, att_src1, att_dst1, xp, a_src, a_dst, Nn, 128);
  gat_gather<<<(Nn + 3) / 4, 256, 0, stream>>>(rowstart, counts, srcs, eas, xp,
                                               a_src, a_dst, params, 1, b1, h1,
                                               nullptr, nullptr, Nn);
  // ---- layer 2 ----
  gemm_attn<<<(Nn + BM - 1) / BM, 256, 0, stream>>>(
      h1, W2, att_src2, att_dst2, xp, a_src, a_dst, Nn, 64);
  gat_gather<<<(Nn + 3) / 4, 256, 0, stream>>>(rowstart, counts, srcs, eas, xp,
                                               a_src, a_dst, params, 3, b2,
                                               nullptr, lin_w, dotv, Nn);
  // ---- pool + linear ----
  pool_lin<<<Gg, 64, 0, stream>>>(dotv, batch, Nn, Gg, lin_b, out);
}

// Round 3
// 295.865 us; speedup vs baseline: 1.4610x; 1.0648x over previous
//
#include <hip/hip_runtime.h>

// ---------------------------------------------------------------------------
// RouteGNN: 2-layer GAT (H=2, C=64, edge_dim=1, concat=False) + mean-pool + lin
// N=50000 nodes, E=800000 edges (+N self loops), G=256 graphs. All fp32.
// R2: ordered CSR (3-phase scan), dst-partitioned count/fill (blockIdx&7 ~= XCD
// under round-robin dispatch -> each payload line written by one XCD's L2),
// int2 edge payload {src, ea} (one 8B store/edge).
// ---------------------------------------------------------------------------

#define NEG_SLOPE 0.2f

__device__ __forceinline__ float wred_sum(float v) {
#pragma unroll
  for (int m = 32; m; m >>= 1) v += __shfl_xor(v, m);
  return v;
}
__device__ __forceinline__ float wred_max(float v) {
#pragma unroll
  for (int m = 32; m; m >>= 1) v = fmaxf(v, __shfl_xor(v, m));
  return v;
}
__device__ __forceinline__ float lrelu(float x) {
  return x > 0.0f ? x : NEG_SLOPE * x;
}

// ---------------- edge_attr mean partials ----------------------------------
__global__ void mean_partial(const float* __restrict__ ea, int E,
                             float* __restrict__ partials) {
  __shared__ float sm[256];
  float s = 0.f;
  for (int i = blockIdx.x * 256 + threadIdx.x; i < E; i += gridDim.x * 256)
    s += ea[i];
  sm[threadIdx.x] = s;
  __syncthreads();
  for (int off = 128; off; off >>= 1) {
    if (threadIdx.x < off) sm[threadIdx.x] += sm[threadIdx.x + off];
    __syncthreads();
  }
  if (threadIdx.x == 0) partials[blockIdx.x] = sm[0];
}

// params[0]=mean(edge_attr); params[1..2]=s_h layer1; params[3..4]=s_h layer2
__global__ void finalize_params(const float* __restrict__ partials, int nparts,
                                int E, const float* __restrict__ We1,
                                const float* __restrict__ atte1,
                                const float* __restrict__ We2,
                                const float* __restrict__ atte2,
                                float* __restrict__ params) {
  __shared__ float sm[256];
  int t = threadIdx.x;
  float s = 0.f;
  for (int i = t; i < nparts; i += 256) s += partials[i];
  sm[t] = s;
  __syncthreads();
  for (int off = 128; off; off >>= 1) {
    if (t < off) sm[t] += sm[t + off];
    __syncthreads();
  }
  if (t == 0) params[0] = sm[0] / (float)E;
  __syncthreads();
  int l = t >> 7, h = (t >> 6) & 1, c = t & 63;
  float p = (l == 0) ? We1[h * 64 + c] * atte1[h * 64 + c]
                     : We2[h * 64 + c] * atte2[h * 64 + c];
  sm[t] = p;
  __syncthreads();
  for (int off = 32; off; off >>= 1) {
    if (c < off) sm[t] += sm[t + off];
    __syncthreads();
  }
  if (c == 0) params[1 + l * 2 + h] = sm[t];
}

// ---------------- dst-partitioned degree count -----------------------------
// grid = 8 * chunks; partition p = blockIdx&7 counts only dst in its range.
__global__ void count_part(const int* __restrict__ ei, int E, int N,
                           int* __restrict__ counts) {
  int p = blockIdx.x & 7;
  int i = (blockIdx.x >> 3) * blockDim.x + threadIdx.x;
  if (i >= E) return;
  int d = ei[E + i];
  int part = (N + 7) >> 3;
  int lo = p * part;
  if (d >= lo && d < lo + part) atomicAdd(&counts[d], 1);
}

// ---------------- 3-phase exclusive scan of (counts[n]+1) ------------------
// scan1: per-block sums (block = 1024 nodes, 256 thr x 4)
__global__ void scan1(const int* __restrict__ counts, int N,
                      int* __restrict__ bsum) {
  __shared__ int wsum[4];
  int t = threadIdx.x;
  int base = blockIdx.x * 1024 + t * 4;
  int s = 0;
#pragma unroll
  for (int k = 0; k < 4; ++k) {
    int n = base + k;
    if (n < N) s += counts[n] + 1;
  }
  s = (int)wred_sum((float)s);  // small ints: exact in fp32? avoid — do int shfl
  // NOTE: use integer shuffle reduce instead (above line replaced below)
  if (false) {}
  // integer wave reduce:
  // (we overwrite s from scratch to be safe)
  {
    int v = 0;
#pragma unroll
    for (int k = 0; k < 4; ++k) {
      int n = base + k;
      if (n < N) v += counts[n] + 1;
    }
#pragma unroll
    for (int m = 32; m; m >>= 1) v += __shfl_xor(v, m);
    s = v;
  }
  int wid = t >> 6, lane = t & 63;
  if (lane == 0) wsum[wid] = s;
  __syncthreads();
  if (t == 0) bsum[blockIdx.x] = wsum[0] + wsum[1] + wsum[2] + wsum[3];
}

// scan2: one wave, exclusive scan of bsum[0..nb)
__global__ void scan2(int* __restrict__ bsum, int nb) {
  int lane = threadIdx.x;
  int base = 0;
  for (int i0 = 0; i0 < nb; i0 += 64) {
    int i = i0 + lane;
    int orig = (i < nb) ? bsum[i] : 0;
    int v = orig;
#pragma unroll
    for (int off = 1; off < 64; off <<= 1) {
      int u = __shfl_up(v, off);
      if (lane >= off) v += u;
    }
    if (i < nb) bsum[i] = base + v - orig;
    base += __shfl(v, 63);
  }
}

// scan3: rowstart[n] (ordered), deg[n]=counts[n]+1, self-loop payload at
// segment end.
__global__ void scan3(const int* __restrict__ counts, int N,
                      const int* __restrict__ bsum, int* __restrict__ rowstart,
                      int* __restrict__ deg, int2* __restrict__ pay,
                      const float* __restrict__ params) {
  __shared__ int wsum[4];
  int t = threadIdx.x;
  int wid = t >> 6, lane = t & 63;
  int base = blockIdx.x * 1024 + t * 4;
  int c[4];
  int s = 0;
#pragma unroll
  for (int k = 0; k < 4; ++k) {
    int n = base + k;
    c[k] = (n < N) ? counts[n] + 1 : 0;
    s += c[k];
  }
  int v = s;
#pragma unroll
  for (int off = 1; off < 64; off <<= 1) {
    int u = __shfl_up(v, off);
    if (lane >= off) v += u;
  }
  int excl = v - s;
  if (lane == 63) wsum[wid] = v;
  __syncthreads();
  int woff = 0;
  for (int k = 0; k < wid; ++k) woff += wsum[k];
  int run = bsum[blockIdx.x] + woff + excl;
  float mean = params[0];
#pragma unroll
  for (int k = 0; k < 4; ++k) {
    int n = base + k;
    if (n < N) {
      rowstart[n] = run;
      deg[n] = c[k];
      int2 pl;
      pl.x = n;
      pl.y = __float_as_int(mean);
      pay[run + c[k] - 1] = pl;  // self-loop at end of segment
      run += c[k];
    }
  }
}

// ---------------- dst-partitioned CSR fill ---------------------------------
// slot via atomicSub(counts) (consumes counts -> zero afterwards).
__global__ void fill_part(const int* __restrict__ ei,
                          const float* __restrict__ eattr, int E, int N,
                          const int* __restrict__ rowstart,
                          int* __restrict__ counts, int2* __restrict__ pay) {
  int p = blockIdx.x & 7;
  int i = (blockIdx.x >> 3) * blockDim.x + threadIdx.x;
  if (i >= E) return;
  int d = ei[E + i];
  int part = (N + 7) >> 3;
  int lo = p * part;
  if (d < lo || d >= lo + part) return;
  int slot = atomicSub(&counts[d], 1) - 1;
  int2 pl;
  pl.x = ei[i];
  pl.y = __float_as_int(eattr[i]);
  pay[rowstart[d] + slot] = pl;
}

// ---------------- SGEMM + fused attention dots -----------------------------
#define BM 64
#define BK 32
__global__ __launch_bounds__(256) void gemm_attn(
    const float* __restrict__ X, const float* __restrict__ W,
    const float* __restrict__ att_src, const float* __restrict__ att_dst,
    float* __restrict__ Y, float* __restrict__ a_src,
    float* __restrict__ a_dst, int N, int K) {
  __shared__ float As[BK][BM + 1];
  __shared__ float Bs[BK][128];
  int t = threadIdx.x;
  int tx = t & 15;
  int ty = t >> 4;
  int rowBase = blockIdx.x * BM;
  float acc[4][8];
#pragma unroll
  for (int r = 0; r < 4; ++r)
#pragma unroll
    for (int c = 0; c < 8; ++c) acc[r][c] = 0.f;

  for (int k0 = 0; k0 < K; k0 += BK) {
#pragma unroll
    for (int v = t; v < BM * BK / 4; v += 256) {
      int r = v >> 3;
      int cv = v & 7;
      int gr = rowBase + r;
      float4 a = make_float4(0.f, 0.f, 0.f, 0.f);
      if (gr < N) a = *(const float4*)(X + (size_t)gr * K + k0 + cv * 4);
      As[cv * 4 + 0][r] = a.x;
      As[cv * 4 + 1][r] = a.y;
      As[cv * 4 + 2][r] = a.z;
      As[cv * 4 + 3][r] = a.w;
    }
#pragma unroll
    for (int v = t; v < BK * 128 / 4; v += 256) {
      int r = v >> 5;
      int cv = v & 31;
      *(float4*)&Bs[r][cv * 4] =
          *(const float4*)(W + (size_t)(k0 + r) * 128 + cv * 4);
    }
    __syncthreads();
#pragma unroll
    for (int kk = 0; kk < BK; ++kk) {
      float a[4], b[8];
#pragma unroll
      for (int r = 0; r < 4; ++r) a[r] = As[kk][ty * 4 + r];
#pragma unroll
      for (int c = 0; c < 8; ++c) b[c] = Bs[kk][tx * 8 + c];
#pragma unroll
      for (int r = 0; r < 4; ++r)
#pragma unroll
        for (int c = 0; c < 8; ++c) acc[r][c] = fmaf(a[r], b[c], acc[r][c]);
    }
    __syncthreads();
  }

  float attS[8], attD[8];
#pragma unroll
  for (int c = 0; c < 8; ++c) {
    attS[c] = att_src[tx * 8 + c];
    attD[c] = att_dst[tx * 8 + c];
  }
#pragma unroll
  for (int r = 0; r < 4; ++r) {
    int gr = rowBase + ty * 4 + r;
    float ps = 0.f, pd = 0.f;
#pragma unroll
    for (int c = 0; c < 8; ++c) {
      ps = fmaf(acc[r][c], attS[c], ps);
      pd = fmaf(acc[r][c], attD[c], pd);
    }
#pragma unroll
    for (int m = 1; m < 8; m <<= 1) {
      ps += __shfl_xor(ps, m);
      pd += __shfl_xor(pd, m);
    }
    if (gr < N) {
      if ((t & 7) == 0) {
        int h = (t >> 3) & 1;
        a_src[gr * 2 + h] = ps;
        a_dst[gr * 2 + h] = pd;
      }
      float4 o0 = make_float4(acc[r][0], acc[r][1], acc[r][2], acc[r][3]);
      float4 o1 = make_float4(acc[r][4], acc[r][5], acc[r][6], acc[r][7]);
      *(float4*)(Y + (size_t)gr * 128 + tx * 8) = o0;
      *(float4*)(Y + (size_t)gr * 128 + tx * 8 + 4) = o1;
    }
  }
}

// ---------------- fused gather: softmax-attention aggregate ----------------
__global__ void gat_gather(const int* __restrict__ rowstart,
                           const int* __restrict__ deg,
                           const int2* __restrict__ pay,
                           const float* __restrict__ xp,
                           const float* __restrict__ a_src,
                           const float* __restrict__ a_dst,
                           const float* __restrict__ params, int sbase,
                           const float* __restrict__ bias,
                           float* __restrict__ hout,
                           const float* __restrict__ lin_w,
                           float* __restrict__ dotout, int N) {
  __shared__ float sm_c[4][128];
  __shared__ int sm_s[4][64];
  int wid = threadIdx.x >> 6, lane = threadIdx.x & 63;
  int n = blockIdx.x * 4 + wid;
  if (n >= N) return;
  int beg = rowstart[n];
  int dg = deg[n];  // includes self-loop
  float s0 = params[sbase], s1 = params[sbase + 1];
  float ad0 = a_dst[n * 2 + 0], ad1 = a_dst[n * 2 + 1];

  if (dg <= 64) {
    float al0 = -1e30f, al1 = -1e30f;
    int myS = n;
    if (lane < dg) {
      int2 pe = pay[beg + lane];
      myS = pe.x;
      float eav = __int_as_float(pe.y);
      float2 as = *(const float2*)(a_src + (size_t)myS * 2);
      al0 = lrelu(as.x + ad0 + eav * s0);
      al1 = lrelu(as.y + ad1 + eav * s1);
    }
    float m0 = wred_max(al0), m1 = wred_max(al1);
    float e0 = __expf(al0 - m0), e1 = __expf(al1 - m1);
    float sum0 = wred_sum(e0), sum1 = wred_sum(e1);
    float c0 = e0 / sum0, c1 = e1 / sum1;
    sm_c[wid][lane * 2 + 0] = c0;
    sm_c[wid][lane * 2 + 1] = c1;
    sm_s[wid][lane] = myS;

    int half = lane >> 5;
    int l5 = lane & 31;
    int h = (lane >> 4) & 1;
    float4 acc = make_float4(0.f, 0.f, 0.f, 0.f);
    int iters = (dg + 1) >> 1;

    int e = half;
    int s = sm_s[wid][e];
    float c = sm_c[wid][e * 2 + h];
    float4 v = ((const float4*)(xp + (size_t)s * 128))[l5];
    for (int i = 1; i < iters; ++i) {
      int e2 = 2 * i + half;
      int s2 = sm_s[wid][e2];
      float c2 = sm_c[wid][e2 * 2 + h];
      float4 v2 = ((const float4*)(xp + (size_t)s2 * 128))[l5];
      acc.x = fmaf(c, v.x, acc.x);
      acc.y = fmaf(c, v.y, acc.y);
      acc.z = fmaf(c, v.z, acc.z);
      acc.w = fmaf(c, v.w, acc.w);
      c = c2;
      v = v2;
    }
    acc.x = fmaf(c, v.x, acc.x);
    acc.y = fmaf(c, v.y, acc.y);
    acc.z = fmaf(c, v.z, acc.z);
    acc.w = fmaf(c, v.w, acc.w);

    acc.x += __shfl_xor(acc.x, 32);
    acc.y += __shfl_xor(acc.y, 32);
    acc.z += __shfl_xor(acc.z, 32);
    acc.w += __shfl_xor(acc.w, 32);
    float4 oth;
    oth.x = __shfl_xor(acc.x, 16);
    oth.y = __shfl_xor(acc.y, 16);
    oth.z = __shfl_xor(acc.z, 16);
    oth.w = __shfl_xor(acc.w, 16);

    float p = 0.f;
    if (lane < 16) {
      float4 b = *(const float4*)(bias + lane * 4);
      float4 o;
      o.x = fmaxf(0.5f * (acc.x + oth.x) + b.x, 0.f);
      o.y = fmaxf(0.5f * (acc.y + oth.y) + b.y, 0.f);
      o.z = fmaxf(0.5f * (acc.z + oth.z) + b.z, 0.f);
      o.w = fmaxf(0.5f * (acc.w + oth.w) + b.w, 0.f);
      if (hout) {
        *(float4*)(hout + (size_t)n * 64 + lane * 4) = o;
      } else {
        float4 lw = *(const float4*)(lin_w + lane * 4);
        p = o.x * lw.x + o.y * lw.y + o.z * lw.z + o.w * lw.w;
      }
    }
    if (!hout) {
      p = wred_sum(p);
      if (lane == 0) dotout[n] = p;
    }
  } else {
    int end = beg + dg;
    float m0 = -1e30f, m1 = -1e30f;
    for (int e = beg + lane; e < end; e += 64) {
      int2 pe = pay[e];
      float eav = __int_as_float(pe.y);
      float2 as = *(const float2*)(a_src + (size_t)pe.x * 2);
      m0 = fmaxf(m0, lrelu(as.x + ad0 + eav * s0));
      m1 = fmaxf(m1, lrelu(as.y + ad1 + eav * s1));
    }
    m0 = wred_max(m0);
    m1 = wred_max(m1);
    float sum0 = 0.f, sum1 = 0.f;
    for (int e = beg + lane; e < end; e += 64) {
      int2 pe = pay[e];
      float eav = __int_as_float(pe.y);
      float2 as = *(const float2*)(a_src + (size_t)pe.x * 2);
      sum0 += __expf(lrelu(as.x + ad0 + eav * s0) - m0);
      sum1 += __expf(lrelu(as.y + ad1 + eav * s1) - m1);
    }
    sum0 = wred_sum(sum0);
    sum1 = wred_sum(sum1);
    float inv0 = 1.f / sum0, inv1 = 1.f / sum1;
    float acc0 = 0.f, acc1 = 0.f;
    for (int base = beg; base < end; base += 64) {
      float c0 = 0.f, c1 = 0.f;
      int cs = n;
      int e = base + lane;
      if (e < end) {
        int2 pe = pay[e];
        float eav = __int_as_float(pe.y);
        float2 as = *(const float2*)(a_src + (size_t)pe.x * 2);
        c0 = __expf(lrelu(as.x + ad0 + eav * s0) - m0) * inv0;
        c1 = __expf(lrelu(as.y + ad1 + eav * s1) - m1) * inv1;
        cs = pe.x;
      }
      int cnt = min(64, end - base);
      for (int i = 0; i < cnt; ++i) {
        float cc0 = __shfl(c0, i);
        float cc1 = __shfl(c1, i);
        int s2 = __shfl(cs, i);
        const float* row = xp + (size_t)s2 * 128;
        acc0 = fmaf(cc0, row[lane], acc0);
        acc1 = fmaf(cc1, row[64 + lane], acc1);
      }
    }
    float val = fmaxf(0.5f * (acc0 + acc1) + bias[lane], 0.f);
    if (hout) {
      hout[(size_t)n * 64 + lane] = val;
    } else {
      float p = wred_sum(val * lin_w[lane]);
      if (lane == 0) dotout[n] = p;
    }
  }
}

// ---------------- pooling + final linear ------------------------------------
__device__ __forceinline__ int lowerb(const int* b, int n, int v) {
  int lo = 0, hi = n;
  while (lo < hi) {
    int mid = (lo + hi) >> 1;
    if (b[mid] < v)
      lo = mid + 1;
    else
      hi = mid;
  }
  return lo;
}

__global__ void pool_lin(const float* __restrict__ dot,
                         const int* __restrict__ batch, int N, int G,
                         const float* __restrict__ lin_b,
                         float* __restrict__ out) {
  int g = blockIdx.x;
  int lane = threadIdx.x;
  int beg = lowerb(batch, N, g);
  int end = lowerb(batch, N, g + 1);
  float s = 0.f;
  for (int i = beg + lane; i < end; i += 64) s += dot[i];
  s = wred_sum(s);
  if (lane == 0) {
    float cnt = fmaxf((float)(end - beg), 1.0f);
    out[g] = s / cnt + lin_b[0];
  }
}

// ---------------------------------------------------------------------------
extern "C" void kernel_launch(void* const* d_in, const int* in_sizes, int n_in,
                              void* d_out, int out_size, void* d_ws,
                              size_t ws_size, hipStream_t stream) {
  const float* x = (const float*)d_in[0];
  const int* ei = (const int*)d_in[1];
  const float* eattr = (const float*)d_in[2];
  const int* batch = (const int*)d_in[3];
  const float* W1 = (const float*)d_in[4];
  const float* att_src1 = (const float*)d_in[5];
  const float* att_dst1 = (const float*)d_in[6];
  const float* We1 = (const float*)d_in[7];
  const float* att_e1 = (const float*)d_in[8];
  const float* b1 = (const float*)d_in[9];
  const float* W2 = (const float*)d_in[10];
  const float* att_src2 = (const float*)d_in[11];
  const float* att_dst2 = (const float*)d_in[12];
  const float* We2 = (const float*)d_in[13];
  const float* att_e2 = (const float*)d_in[14];
  const float* b2 = (const float*)d_in[15];
  const float* lin_w = (const float*)d_in[16];
  const float* lin_b = (const float*)d_in[17];
  float* out = (float*)d_out;

  const int Nn = in_sizes[0] / 128;  // 50000
  const int Ee = in_sizes[2];        // 800000
  const int Etot = Ee + Nn;
  const int Gg = out_size;           // 256

  char* ws = (char*)d_ws;
  size_t off = 0;
  auto alloc = [&](size_t bytes) -> char* {
    char* p = ws + off;
    off += (bytes + 255) & ~(size_t)255;
    return p;
  };
  float* params = (float*)alloc(8 * 4);
  float* partials = (float*)alloc(512 * 4);
  int* counts = (int*)alloc((size_t)Nn * 4);
  int* degarr = (int*)alloc((size_t)Nn * 4);
  int* rowstart = (int*)alloc((size_t)Nn * 4);
  int* bsum = (int*)alloc(256 * 4);
  int2* pay = (int2*)alloc((size_t)Etot * 8);
  float* a_src = (float*)alloc((size_t)Nn * 2 * 4);
  float* a_dst = (float*)alloc((size_t)Nn * 2 * 4);
  float* xp = (float*)alloc((size_t)Nn * 128 * 4);
  float* h1 = (float*)alloc((size_t)Nn * 64 * 4);
  float* dotv = (float*)alloc((size_t)Nn * 4);

  hipMemsetAsync(counts, 0, (size_t)Nn * 4, stream);

  const int chunks = (Ee + 511) / 512;   // partitioned kernels: 8*chunks blocks
  const int nb = (Nn + 1023) / 1024;     // scan blocks

  mean_partial<<<512, 256, 0, stream>>>(eattr, Ee, partials);
  finalize_params<<<1, 256, 0, stream>>>(partials, 512, Ee, We1, att_e1, We2,
                                         att_e2, params);
  count_part<<<8 * chunks, 512, 0, stream>>>(ei, Ee, Nn, counts);
  scan1<<<nb, 256, 0, stream>>>(counts, Nn, bsum);
  scan2<<<1, 64, 0, stream>>>(bsum, nb);
  scan3<<<nb, 256, 0, stream>>>(counts, Nn, bsum, rowstart, degarr, pay,
                                params);
  fill_part<<<8 * chunks, 512, 0, stream>>>(ei, eattr, Ee, Nn, rowstart,
                                            counts, pay);

  // ---- layer 1 ----
  gemm_attn<<<(Nn + BM - 1) / BM, 256, 0, stream>>>(
      x, W1, att_src1, att_dst1, xp, a_src, a_dst, Nn, 128);
  gat_gather<<<(Nn + 3) / 4, 256, 0, stream>>>(rowstart, degarr, pay, xp,
                                               a_src, a_dst, params, 1, b1, h1,
                                               nullptr, nullptr, Nn);
  // ---- layer 2 ----
  gemm_attn<<<(Nn + BM - 1) / BM, 256, 0, stream>>>(
      h1, W2, att_src2, att_dst2, xp, a_src, a_dst, Nn, 64);
  gat_gather<<<(Nn + 3) / 4, 256, 0, stream>>>(rowstart, degarr, pay, xp,
                                               a_src, a_dst, params, 3, b2,
                                               nullptr, lin_w, dotv, Nn);
  // ---- pool + linear ----
  pool_lin<<<Gg, 64, 0, stream>>>(dotv, batch, Nn, Gg, lin_b, out);
}